// Round 5
// baseline (290.797 us; speedup 1.0000x reference)
//
#include <hip/hip_runtime.h>
#include <math.h>

#define N_NODES 50000
#define NPAD    50048      // 391 * 128
#define F_IN    128
#define HID     256
#define NCLS    40
#define WPAD    64         // padded hW width

typedef __attribute__((ext_vector_type(8))) short bf16x8;
typedef __attribute__((ext_vector_type(4))) float f32x4;

__device__ inline ushort f2bf(float f) {
    uint u = __builtin_bit_cast(uint, f);
    u += 0x7FFF + ((u >> 16) & 1);          // round-to-nearest-even
    return (ushort)(u >> 16);
}
__device__ inline float bf2f(uint h16) {
    uint u = h16 << 16;
    return __builtin_bit_cast(float, u);
}

// ---------------- prep: zero cnt + cast x->bf16 + pack weights (one dispatch) ----------------
// blocks [0,196): cnt zero; [196,6446): cast_x (exactly 1.6M float4); [6446,6782): weight pack

__global__ void prep_kernel(const float* __restrict__ x, ushort* __restrict__ xb,
                            const float* __restrict__ W1l, const float* __restrict__ W1r,
                            const float* __restrict__ W2l, const float* __restrict__ W2r,
                            ushort* __restrict__ Wb1, ushort* __restrict__ Wb2,
                            int* __restrict__ cnt) {
    int b = blockIdx.x, t = threadIdx.x;
    if (b < 196) {
        int i = b * 256 + t;
        if (i < N_NODES) cnt[i] = 0;
    } else if (b < 6446) {
        int i = (b - 196) * 256 + t;     // < 1,600,000 exactly
        float4 v = *reinterpret_cast<const float4*>(x + (size_t)i * 4);
        ushort4 o;
        o.x = f2bf(v.x); o.y = f2bf(v.y); o.z = f2bf(v.z); o.w = f2bf(v.w);
        *reinterpret_cast<ushort4*>(xb + (size_t)i * 4) = o;
    } else {
        int i = (b - 6446) * 256 + t;    // < 86016 exactly
        if (i < 65536) {
            int n = i >> 8, k = i & 255;
            float v = (k < 128) ? W1l[n * 128 + k] : W1r[n * 128 + (k - 128)];
            Wb1[i] = f2bf(v);
        } else {
            int j = i - 65536;           // < 20480
            int n = j >> 8, k = j & 255;
            float v = (n < 40) ? W2l[n * 256 + k] : W2r[(n - 40) * 256 + k];
            Wb2[j] = f2bf(v);
        }
    }
}

// ---------------- CSR build ----------------

__global__ void count_kernel(const int* __restrict__ dst, int* __restrict__ cnt, int E) {
    int i = blockIdx.x * blockDim.x + threadIdx.x;
    if (i < E) atomicAdd(&cnt[dst[i]], 1);
}

// single-block exclusive scan of cnt[0..N) -> rowstart/fillpos
__global__ __launch_bounds__(1024) void scan_one_kernel(const int* __restrict__ cnt,
                                                        int* __restrict__ rowstart,
                                                        int* __restrict__ fillpos,
                                                        int N, int E) {
    __shared__ int sdata[1024];
    const int CH = 49;                       // 1024*49 = 50176 >= N
    int t = threadIdx.x;
    int base = t * CH;
    int s = 0;
    for (int i = 0; i < CH; ++i) {
        int idx = base + i;
        if (idx < N) s += cnt[idx];
    }
    sdata[t] = s;
    __syncthreads();
    for (int off = 1; off < 1024; off <<= 1) {
        int u = (t >= off) ? sdata[t - off] : 0;
        __syncthreads();
        sdata[t] += u;
        __syncthreads();
    }
    int prefix = sdata[t] - s;               // exclusive block prefix
    for (int i = 0; i < CH; ++i) {
        int idx = base + i;
        if (idx < N) {
            rowstart[idx] = prefix;
            fillpos[idx]  = prefix;
            prefix += cnt[idx];
        }
    }
    if (t == 0) rowstart[N] = E;
}

__global__ void fill_kernel(const int* __restrict__ src, const int* __restrict__ dst,
                            int* __restrict__ fillpos, int* __restrict__ col, int E) {
    int i = blockIdx.x * blockDim.x + threadIdx.x;
    if (i < E) {
        int p = atomicAdd(&fillpos[dst[i]], 1);
        col[p] = src[i];
    }
}

// ---------------- mean aggregation layer 1 ----------------
// 4 edges in flight per wave: 4 groups x 16 lanes x 16B

__global__ __launch_bounds__(256) void agg128_kernel(const ushort* __restrict__ xb,
                                                     const int* __restrict__ rowstart,
                                                     const int* __restrict__ col,
                                                     ushort* __restrict__ aggb) {
    int wid = threadIdx.x >> 6, l = threadIdx.x & 63;
    int n = blockIdx.x * 4 + wid;
    if (n >= N_NODES) return;
    int g = l >> 4, lr = l & 15;
    int s = rowstart[n], e = rowstart[n + 1];
    float a[8] = {};
    for (int j = s + g; j < e; j += 4) {
        int c = col[j];
        uint4 v = *reinterpret_cast<const uint4*>(xb + (size_t)c * F_IN + lr * 8);
        a[0] += bf2f(v.x & 0xffffu); a[1] += bf2f(v.x >> 16);
        a[2] += bf2f(v.y & 0xffffu); a[3] += bf2f(v.y >> 16);
        a[4] += bf2f(v.z & 0xffffu); a[5] += bf2f(v.z >> 16);
        a[6] += bf2f(v.w & 0xffffu); a[7] += bf2f(v.w >> 16);
    }
#pragma unroll
    for (int i = 0; i < 8; ++i) {
        a[i] += __shfl_xor(a[i], 16);
        a[i] += __shfl_xor(a[i], 32);
    }
    if (g == 0) {
        float inv = 1.0f / (float)max(e - s, 1);
        uint4 o;
        o.x = (uint)f2bf(a[0] * inv) | ((uint)f2bf(a[1] * inv) << 16);
        o.y = (uint)f2bf(a[2] * inv) | ((uint)f2bf(a[3] * inv) << 16);
        o.z = (uint)f2bf(a[4] * inv) | ((uint)f2bf(a[5] * inv) << 16);
        o.w = (uint)f2bf(a[6] * inv) | ((uint)f2bf(a[7] * inv) << 16);
        *reinterpret_cast<uint4*>(aggb + (size_t)n * F_IN + lr * 8) = o;
    }
}

// ---------------- fused GEMM1+GEMM2 ----------------
// Per block: 128 rows. Phase 1: h = relu([agg|x] @ Wb1.T + b1) with Wb1 staged
// per-128-col half in 64KB LDS. Phase 2: h tile -> same LDS (bf16, swizzled;
// h never touches global). Phase 3: [hW | out_r] = h @ Wb2.T with Wb2 read
// directly from global (L2-hot, 40KB).

__global__ __launch_bounds__(256, 2) void gemm12_kernel(const ushort* __restrict__ aggb,
                                                        const ushort* __restrict__ xb,
                                                        const ushort* __restrict__ Wb1,
                                                        const float* __restrict__ b1,
                                                        const ushort* __restrict__ Wb2,
                                                        const float* __restrict__ b2,
                                                        ushort* __restrict__ hWb,
                                                        float* __restrict__ outp) {
    __shared__ __align__(16) char S[128 * 512];   // 64 KiB: B1-half staging, then h tile
    const int t = threadIdx.x, w = t >> 6, l = t & 63;
    const int bm = blockIdx.x * 128;
    const int lr = l & 15, lg = l >> 4;

    f32x4 acc[2][16] = {};
#pragma unroll
    for (int half = 0; half < 2; ++half) {
        // stage B1 rows [half*128, half*128+128), swizzled
        for (int i = t; i < 128 * 32; i += 256) {
            int n = i >> 5, k8 = (i & 31) * 8;
            uint4 v = *reinterpret_cast<const uint4*>(Wb1 + (size_t)(half * 128 + n) * 256 + k8);
            *reinterpret_cast<uint4*>(S + ((n * 512 + k8 * 2) ^ ((n & 7) << 4))) = v;
        }
        __syncthreads();
#pragma unroll
        for (int kt = 0; kt < 8; ++kt) {
            const ushort* Ap = (kt < 4) ? aggb : xb;
            int kb = kt * 32 - ((kt < 4) ? 0 : 128) + lg * 8;
            bf16x8 a0 = *reinterpret_cast<const bf16x8*>(Ap + (size_t)(bm + w * 32 + lr) * F_IN + kb);
            bf16x8 a1 = *reinterpret_cast<const bf16x8*>(Ap + (size_t)(bm + w * 32 + 16 + lr) * F_IN + kb);
            int kbyte = kt * 64 + lg * 16;
#pragma unroll
            for (int j = 0; j < 8; ++j) {
                int nl = j * 16 + lr;
                bf16x8 b = *reinterpret_cast<const bf16x8*>(S + ((nl * 512 + kbyte) ^ ((nl & 7) << 4)));
                acc[0][half * 8 + j] = __builtin_amdgcn_mfma_f32_16x16x32_bf16(a0, b, acc[0][half * 8 + j], 0, 0, 0);
                acc[1][half * 8 + j] = __builtin_amdgcn_mfma_f32_16x16x32_bf16(a1, b, acc[1][half * 8 + j], 0, 0, 0);
            }
        }
        __syncthreads();   // B reads done before restage / h write
    }

    // write h tile (128 x 256 bf16) into S, swizzled, row stride 512B
#pragma unroll
    for (int j = 0; j < 16; ++j) {
        int c = j * 16 + lr;
        float bias = b1[c];
#pragma unroll
        for (int m = 0; m < 2; ++m) {
            int rowb = w * 32 + m * 16 + lg * 4;
#pragma unroll
            for (int r = 0; r < 4; ++r) {
                float v = fmaxf(acc[m][j][r] + bias, 0.f);
                int row = rowb + r;
                *reinterpret_cast<ushort*>(S + ((row * 512 + c * 2) ^ ((row & 7) << 4))) = f2bf(v);
            }
        }
    }
    __syncthreads();

    // GEMM2: A from LDS h, B = Wb2 from global (L2)
    f32x4 acc2[2][5] = {};
#pragma unroll
    for (int kt = 0; kt < 8; ++kt) {
        int kbyte = kt * 64 + lg * 16;
        int r0 = w * 32 + lr, r1 = r0 + 16;
        bf16x8 a0 = *reinterpret_cast<const bf16x8*>(S + ((r0 * 512 + kbyte) ^ ((r0 & 7) << 4)));
        bf16x8 a1 = *reinterpret_cast<const bf16x8*>(S + ((r1 * 512 + kbyte) ^ ((r1 & 7) << 4)));
#pragma unroll
        for (int j = 0; j < 5; ++j) {
            int nl = j * 16 + lr;
            bf16x8 b = *reinterpret_cast<const bf16x8*>(Wb2 + (size_t)nl * 256 + kt * 32 + lg * 8);
            acc2[0][j] = __builtin_amdgcn_mfma_f32_16x16x32_bf16(a0, b, acc2[0][j], 0, 0, 0);
            acc2[1][j] = __builtin_amdgcn_mfma_f32_16x16x32_bf16(a1, b, acc2[1][j], 0, 0, 0);
        }
    }
#pragma unroll
    for (int m = 0; m < 2; ++m) {
        int rbase = bm + w * 32 + m * 16 + lg * 4;
#pragma unroll
        for (int j = 0; j < 5; ++j) {
            int cfull = j * 16 + lr;
#pragma unroll
            for (int r = 0; r < 4; ++r) {
                int row = rbase + r;
                float v = acc2[m][j][r];
                if (cfull < 40) {
                    hWb[(size_t)row * WPAD + cfull] = f2bf(v);
                } else {
                    if (cfull < 64) hWb[(size_t)row * WPAD + cfull] = 0;  // zero pad cols
                    if (row < N_NODES) {
                        int c = cfull - 40;
                        outp[(size_t)row * NCLS + c] = v + b2[c];
                    }
                }
            }
        }
    }
}

// ---------------- fused: out = log_softmax(out_partial + mean_j hW_j) ----------------
// 8 edges in flight per wave: 8 groups x 8 lanes x 16B (WPAD=64 bf16 rows)

__global__ __launch_bounds__(256) void agg40_lsm_kernel(const ushort* __restrict__ hWb,
                                                        const int* __restrict__ rowstart,
                                                        const int* __restrict__ col,
                                                        float* __restrict__ out) {
    int wid = threadIdx.x >> 6, l = threadIdx.x & 63;
    int n = blockIdx.x * 4 + wid;
    if (n >= N_NODES) return;
    int g = l >> 3, lr = l & 7;
    int s = rowstart[n], e = rowstart[n + 1];
    float a[8] = {};
    for (int j = s + g; j < e; j += 8) {
        int c = col[j];
        uint4 v = *reinterpret_cast<const uint4*>(hWb + (size_t)c * WPAD + lr * 8);
        a[0] += bf2f(v.x & 0xffffu); a[1] += bf2f(v.x >> 16);
        a[2] += bf2f(v.y & 0xffffu); a[3] += bf2f(v.y >> 16);
        a[4] += bf2f(v.z & 0xffffu); a[5] += bf2f(v.z >> 16);
        a[6] += bf2f(v.w & 0xffffu); a[7] += bf2f(v.w >> 16);
    }
#pragma unroll
    for (int i = 0; i < 8; ++i) {
        a[i] += __shfl_xor(a[i], 8);
        a[i] += __shfl_xor(a[i], 16);
        a[i] += __shfl_xor(a[i], 32);
    }
    float inv = 1.0f / (float)max(e - s, 1);
    bool act = (g == 0) && (lr < 5);
    float v[8];
    if (act) {
        const float* pb = out + (size_t)n * NCLS + lr * 8;
        float4 p0 = *reinterpret_cast<const float4*>(pb);
        float4 p1 = *reinterpret_cast<const float4*>(pb + 4);
        v[0] = p0.x + a[0] * inv; v[1] = p0.y + a[1] * inv;
        v[2] = p0.z + a[2] * inv; v[3] = p0.w + a[3] * inv;
        v[4] = p1.x + a[4] * inv; v[5] = p1.y + a[5] * inv;
        v[6] = p1.z + a[6] * inv; v[7] = p1.w + a[7] * inv;
    } else {
#pragma unroll
        for (int i = 0; i < 8; ++i) v[i] = -INFINITY;
    }
    float m = v[0];
#pragma unroll
    for (int i = 1; i < 8; ++i) m = fmaxf(m, v[i]);
    m = fmaxf(m, __shfl_xor(m, 1));
    m = fmaxf(m, __shfl_xor(m, 2));
    m = fmaxf(m, __shfl_xor(m, 4));
    float ex = 0.f;
    if (act) {
#pragma unroll
        for (int i = 0; i < 8; ++i) ex += expf(v[i] - m);
    }
    ex += __shfl_xor(ex, 1);
    ex += __shfl_xor(ex, 2);
    ex += __shfl_xor(ex, 4);
    float ls = logf(ex);
    if (act) {
        float* ob = out + (size_t)n * NCLS + lr * 8;
        float4 o0, o1;
        o0.x = v[0] - m - ls; o0.y = v[1] - m - ls; o0.z = v[2] - m - ls; o0.w = v[3] - m - ls;
        o1.x = v[4] - m - ls; o1.y = v[5] - m - ls; o1.z = v[6] - m - ls; o1.w = v[7] - m - ls;
        *reinterpret_cast<float4*>(ob) = o0;
        *reinterpret_cast<float4*>(ob + 4) = o1;
    }
}

// ---------------- launch ----------------

static inline size_t align256(size_t x) { return (x + 255) & ~(size_t)255; }

extern "C" void kernel_launch(void* const* d_in, const int* in_sizes, int n_in,
                              void* d_out, int out_size, void* d_ws, size_t ws_size,
                              hipStream_t stream) {
    const float* x    = (const float*)d_in[0];
    const int*   ei   = (const int*)d_in[1];
    const float* W1l  = (const float*)d_in[2];
    const float* b1   = (const float*)d_in[3];
    const float* W1r  = (const float*)d_in[4];
    const float* W2l  = (const float*)d_in[5];
    const float* b2   = (const float*)d_in[6];
    const float* W2r  = (const float*)d_in[7];
    float* out = (float*)d_out;

    const int N = N_NODES;
    const int E = in_sizes[1] / 2;
    const int* srcArr = ei;
    const int* dstArr = ei + E;

    char* ws = (char*)d_ws;
    size_t off = 0;
    auto alloc = [&](size_t bytes) { size_t o = off; off = align256(off + bytes); return o; };
    int*    cnt      = (int*)(ws + alloc((size_t)N * 4));
    int*    rowstart = (int*)(ws + alloc((size_t)(N + 1) * 4));
    int*    fillpos  = (int*)(ws + alloc((size_t)N * 4));
    int*    col      = (int*)(ws + alloc((size_t)E * 4));
    ushort* xb       = (ushort*)(ws + alloc((size_t)NPAD * F_IN * 2));
    ushort* aggb     = (ushort*)(ws + alloc((size_t)NPAD * F_IN * 2));
    ushort* hWb      = (ushort*)(ws + alloc((size_t)NPAD * WPAD * 2));
    ushort* Wb1      = (ushort*)(ws + alloc((size_t)256 * 256 * 2));
    ushort* Wb2      = (ushort*)(ws + alloc((size_t)80 * 256 * 2));
    (void)ws_size; (void)n_in; (void)out_size;

    const int nbE = (E + 255) / 256;

    // 1. independent prep (cnt zero + x cast + weight packs)
    prep_kernel<<<6782, 256, 0, stream>>>(x, xb, W1l, W1r, W2l, W2r, Wb1, Wb2, cnt);
    // 2-4. CSR build
    count_kernel<<<nbE, 256, 0, stream>>>(dstArr, cnt, E);
    scan_one_kernel<<<1, 1024, 0, stream>>>(cnt, rowstart, fillpos, N, E);
    fill_kernel<<<nbE, 256, 0, stream>>>(srcArr, dstArr, fillpos, col, E);
    // 5. layer-1 mean aggregation
    agg128_kernel<<<(N + 3) / 4, 256, 0, stream>>>(xb, rowstart, col, aggb);
    // 6. fused gemm1+gemm2 (h stays in LDS)
    gemm12_kernel<<<NPAD / 128, 256, 0, stream>>>(aggb, xb, Wb1, b1, Wb2, b2, hWb, out);
    // 7. layer-2 aggregation + log_softmax
    agg40_lsm_kernel<<<(N + 3) / 4, 256, 0, stream>>>(hWb, rowstart, col, out);
}

// Round 6
// 174.728 us; speedup vs baseline: 1.6643x; 1.6643x over previous
//
#include <hip/hip_runtime.h>
#include <math.h>

#define N_NODES 50000
#define NPAD    50048      // 391 * 128
#define F_IN    128
#define HID     256
#define NCLS    40
#define WPAD    64         // padded hW width

typedef __attribute__((ext_vector_type(8))) short bf16x8;
typedef __attribute__((ext_vector_type(4))) float f32x4;

__device__ inline ushort f2bf(float f) {
    uint u = __builtin_bit_cast(uint, f);
    u += 0x7FFF + ((u >> 16) & 1);          // round-to-nearest-even
    return (ushort)(u >> 16);
}
__device__ inline float bf2f(uint h16) {
    uint u = h16 << 16;
    return __builtin_bit_cast(float, u);
}

// ---------------- prep: zero cnt + cast x->bf16 + pack weights (one dispatch) ----------------
// blocks [0,196): cnt zero; [196,6446): cast_x (exactly 1.6M float4); [6446,6782): weight pack

__global__ void prep_kernel(const float* __restrict__ x, ushort* __restrict__ xb,
                            const float* __restrict__ W1l, const float* __restrict__ W1r,
                            const float* __restrict__ W2l, const float* __restrict__ W2r,
                            ushort* __restrict__ Wb1, ushort* __restrict__ Wb2,
                            int* __restrict__ cnt) {
    int b = blockIdx.x, t = threadIdx.x;
    if (b < 196) {
        int i = b * 256 + t;
        if (i < N_NODES) cnt[i] = 0;
    } else if (b < 6446) {
        int i = (b - 196) * 256 + t;     // < 1,600,000 exactly
        float4 v = *reinterpret_cast<const float4*>(x + (size_t)i * 4);
        ushort4 o;
        o.x = f2bf(v.x); o.y = f2bf(v.y); o.z = f2bf(v.z); o.w = f2bf(v.w);
        *reinterpret_cast<ushort4*>(xb + (size_t)i * 4) = o;
    } else {
        int i = (b - 6446) * 256 + t;    // < 86016 exactly
        if (i < 65536) {
            int n = i >> 8, k = i & 255;
            float v = (k < 128) ? W1l[n * 128 + k] : W1r[n * 128 + (k - 128)];
            Wb1[i] = f2bf(v);
        } else {
            int j = i - 65536;           // < 20480
            int n = j >> 8, k = j & 255;
            float v = (n < 40) ? W2l[n * 256 + k] : W2r[(n - 40) * 256 + k];
            Wb2[j] = f2bf(v);
        }
    }
}

// ---------------- CSR build ----------------

__global__ void count_kernel(const int* __restrict__ dst, int* __restrict__ cnt, int E) {
    int i = blockIdx.x * blockDim.x + threadIdx.x;
    if (i < E) atomicAdd(&cnt[dst[i]], 1);
}

__global__ void block_sum_kernel(const int* __restrict__ cnt, int* __restrict__ bsum, int N) {
    __shared__ int sdata[256];
    int i = blockIdx.x * 256 + threadIdx.x;
    sdata[threadIdx.x] = (i < N) ? cnt[i] : 0;
    __syncthreads();
    for (int off = 128; off; off >>= 1) {
        if (threadIdx.x < off) sdata[threadIdx.x] += sdata[threadIdx.x + off];
        __syncthreads();
    }
    if (threadIdx.x == 0) bsum[blockIdx.x] = sdata[0];
}

__global__ void scan_bsum_kernel(int* bsum, int nb) {
    __shared__ int sdata[1024];
    int t = threadIdx.x;
    int v = (t < nb) ? bsum[t] : 0;
    sdata[t] = v;
    __syncthreads();
    for (int off = 1; off < 1024; off <<= 1) {
        int u = (t >= off) ? sdata[t - off] : 0;
        __syncthreads();
        sdata[t] += u;
        __syncthreads();
    }
    if (t < nb) bsum[t] = sdata[t] - v;   // exclusive
}

__global__ void scan_final_kernel(const int* __restrict__ cnt, const int* __restrict__ bsum,
                                  int* __restrict__ rowstart, int* __restrict__ fillpos,
                                  int N, int E) {
    __shared__ int sdata[256];
    int t = threadIdx.x;
    int i = blockIdx.x * 256 + t;
    int v = (i < N) ? cnt[i] : 0;
    sdata[t] = v;
    __syncthreads();
    for (int off = 1; off < 256; off <<= 1) {
        int u = (t >= off) ? sdata[t - off] : 0;
        __syncthreads();
        sdata[t] += u;
        __syncthreads();
    }
    if (i < N) {
        int r = bsum[blockIdx.x] + sdata[t] - v;
        rowstart[i] = r;
        fillpos[i]  = r;
    }
    if (i == 0) rowstart[N] = E;
}

__global__ void fill_kernel(const int* __restrict__ src, const int* __restrict__ dst,
                            int* __restrict__ fillpos, int* __restrict__ col, int E) {
    int i = blockIdx.x * blockDim.x + threadIdx.x;
    if (i < E) {
        int p = atomicAdd(&fillpos[dst[i]], 1);
        col[p] = src[i];
    }
}

// ---------------- mean aggregation layer 1 ----------------
// 4 edges in flight per wave: 4 groups x 16 lanes x 16B

__global__ __launch_bounds__(256) void agg128_kernel(const ushort* __restrict__ xb,
                                                     const int* __restrict__ rowstart,
                                                     const int* __restrict__ col,
                                                     ushort* __restrict__ aggb) {
    int wid = threadIdx.x >> 6, l = threadIdx.x & 63;
    int n = blockIdx.x * 4 + wid;
    if (n >= N_NODES) return;
    int g = l >> 4, lr = l & 15;
    int s = rowstart[n], e = rowstart[n + 1];
    float a[8] = {};
    for (int j = s + g; j < e; j += 4) {
        int c = col[j];
        uint4 v = *reinterpret_cast<const uint4*>(xb + (size_t)c * F_IN + lr * 8);
        a[0] += bf2f(v.x & 0xffffu); a[1] += bf2f(v.x >> 16);
        a[2] += bf2f(v.y & 0xffffu); a[3] += bf2f(v.y >> 16);
        a[4] += bf2f(v.z & 0xffffu); a[5] += bf2f(v.z >> 16);
        a[6] += bf2f(v.w & 0xffffu); a[7] += bf2f(v.w >> 16);
    }
#pragma unroll
    for (int i = 0; i < 8; ++i) {
        a[i] += __shfl_xor(a[i], 16);
        a[i] += __shfl_xor(a[i], 32);
    }
    if (g == 0) {
        float inv = 1.0f / (float)max(e - s, 1);
        uint4 o;
        o.x = (uint)f2bf(a[0] * inv) | ((uint)f2bf(a[1] * inv) << 16);
        o.y = (uint)f2bf(a[2] * inv) | ((uint)f2bf(a[3] * inv) << 16);
        o.z = (uint)f2bf(a[4] * inv) | ((uint)f2bf(a[5] * inv) << 16);
        o.w = (uint)f2bf(a[6] * inv) | ((uint)f2bf(a[7] * inv) << 16);
        *reinterpret_cast<uint4*>(aggb + (size_t)n * F_IN + lr * 8) = o;
    }
}

// ---------------- fused GEMM1+GEMM2 ----------------
// Per block: 128 rows. Phase 1: h = relu([agg|x] @ Wb1.T + b1) with Wb1 staged
// per-128-col half in 64KB LDS. Phase 2: h tile -> same LDS (bf16, swizzled;
// h never touches global). Phase 3: [hW | out_r] = h @ Wb2.T with Wb2 read
// directly from global (L2-hot, 40KB).

__global__ __launch_bounds__(256, 2) void gemm12_kernel(const ushort* __restrict__ aggb,
                                                        const ushort* __restrict__ xb,
                                                        const ushort* __restrict__ Wb1,
                                                        const float* __restrict__ b1,
                                                        const ushort* __restrict__ Wb2,
                                                        const float* __restrict__ b2,
                                                        ushort* __restrict__ hWb,
                                                        float* __restrict__ outp) {
    __shared__ __align__(16) char S[128 * 512];   // 64 KiB: B1-half staging, then h tile
    const int t = threadIdx.x, w = t >> 6, l = t & 63;
    const int bm = blockIdx.x * 128;
    const int lr = l & 15, lg = l >> 4;

    f32x4 acc[2][16] = {};
#pragma unroll
    for (int half = 0; half < 2; ++half) {
        // stage B1 rows [half*128, half*128+128), swizzled
        for (int i = t; i < 128 * 32; i += 256) {
            int n = i >> 5, k8 = (i & 31) * 8;
            uint4 v = *reinterpret_cast<const uint4*>(Wb1 + (size_t)(half * 128 + n) * 256 + k8);
            *reinterpret_cast<uint4*>(S + ((n * 512 + k8 * 2) ^ ((n & 7) << 4))) = v;
        }
        __syncthreads();
#pragma unroll
        for (int kt = 0; kt < 8; ++kt) {
            const ushort* Ap = (kt < 4) ? aggb : xb;
            int kb = kt * 32 - ((kt < 4) ? 0 : 128) + lg * 8;
            bf16x8 a0 = *reinterpret_cast<const bf16x8*>(Ap + (size_t)(bm + w * 32 + lr) * F_IN + kb);
            bf16x8 a1 = *reinterpret_cast<const bf16x8*>(Ap + (size_t)(bm + w * 32 + 16 + lr) * F_IN + kb);
            int kbyte = kt * 64 + lg * 16;
#pragma unroll
            for (int j = 0; j < 8; ++j) {
                int nl = j * 16 + lr;
                bf16x8 b = *reinterpret_cast<const bf16x8*>(S + ((nl * 512 + kbyte) ^ ((nl & 7) << 4)));
                acc[0][half * 8 + j] = __builtin_amdgcn_mfma_f32_16x16x32_bf16(a0, b, acc[0][half * 8 + j], 0, 0, 0);
                acc[1][half * 8 + j] = __builtin_amdgcn_mfma_f32_16x16x32_bf16(a1, b, acc[1][half * 8 + j], 0, 0, 0);
            }
        }
        __syncthreads();   // B reads done before restage / h write
    }

    // write h tile (128 x 256 bf16) into S, swizzled, row stride 512B
#pragma unroll
    for (int j = 0; j < 16; ++j) {
        int c = j * 16 + lr;
        float bias = b1[c];
#pragma unroll
        for (int m = 0; m < 2; ++m) {
            int rowb = w * 32 + m * 16 + lg * 4;
#pragma unroll
            for (int r = 0; r < 4; ++r) {
                float v = fmaxf(acc[m][j][r] + bias, 0.f);
                int row = rowb + r;
                *reinterpret_cast<ushort*>(S + ((row * 512 + c * 2) ^ ((row & 7) << 4))) = f2bf(v);
            }
        }
    }
    __syncthreads();

    // GEMM2: A from LDS h, B = Wb2 from global (L2)
    f32x4 acc2[2][5] = {};
#pragma unroll
    for (int kt = 0; kt < 8; ++kt) {
        int kbyte = kt * 64 + lg * 16;
        int r0 = w * 32 + lr, r1 = r0 + 16;
        bf16x8 a0 = *reinterpret_cast<const bf16x8*>(S + ((r0 * 512 + kbyte) ^ ((r0 & 7) << 4)));
        bf16x8 a1 = *reinterpret_cast<const bf16x8*>(S + ((r1 * 512 + kbyte) ^ ((r1 & 7) << 4)));
#pragma unroll
        for (int j = 0; j < 5; ++j) {
            int nl = j * 16 + lr;
            bf16x8 b = *reinterpret_cast<const bf16x8*>(Wb2 + (size_t)nl * 256 + kt * 32 + lg * 8);
            acc2[0][j] = __builtin_amdgcn_mfma_f32_16x16x32_bf16(a0, b, acc2[0][j], 0, 0, 0);
            acc2[1][j] = __builtin_amdgcn_mfma_f32_16x16x32_bf16(a1, b, acc2[1][j], 0, 0, 0);
        }
    }
#pragma unroll
    for (int m = 0; m < 2; ++m) {
        int rbase = bm + w * 32 + m * 16 + lg * 4;
#pragma unroll
        for (int j = 0; j < 5; ++j) {
            int cfull = j * 16 + lr;
#pragma unroll
            for (int r = 0; r < 4; ++r) {
                int row = rbase + r;
                float v = acc2[m][j][r];
                if (cfull < 40) {
                    hWb[(size_t)row * WPAD + cfull] = f2bf(v);
                } else {
                    if (cfull < 64) hWb[(size_t)row * WPAD + cfull] = 0;  // zero pad cols
                    if (row < N_NODES) {
                        int c = cfull - 40;
                        outp[(size_t)row * NCLS + c] = v + b2[c];
                    }
                }
            }
        }
    }
}

// ---------------- fused: out = log_softmax(out_partial + mean_j hW_j) ----------------
// 8 edges in flight per wave: 8 groups x 8 lanes x 16B (WPAD=64 bf16 rows)

__global__ __launch_bounds__(256) void agg40_lsm_kernel(const ushort* __restrict__ hWb,
                                                        const int* __restrict__ rowstart,
                                                        const int* __restrict__ col,
                                                        float* __restrict__ out) {
    int wid = threadIdx.x >> 6, l = threadIdx.x & 63;
    int n = blockIdx.x * 4 + wid;
    if (n >= N_NODES) return;
    int g = l >> 3, lr = l & 7;
    int s = rowstart[n], e = rowstart[n + 1];
    float a[8] = {};
    for (int j = s + g; j < e; j += 8) {
        int c = col[j];
        uint4 v = *reinterpret_cast<const uint4*>(hWb + (size_t)c * WPAD + lr * 8);
        a[0] += bf2f(v.x & 0xffffu); a[1] += bf2f(v.x >> 16);
        a[2] += bf2f(v.y & 0xffffu); a[3] += bf2f(v.y >> 16);
        a[4] += bf2f(v.z & 0xffffu); a[5] += bf2f(v.z >> 16);
        a[6] += bf2f(v.w & 0xffffu); a[7] += bf2f(v.w >> 16);
    }
#pragma unroll
    for (int i = 0; i < 8; ++i) {
        a[i] += __shfl_xor(a[i], 8);
        a[i] += __shfl_xor(a[i], 16);
        a[i] += __shfl_xor(a[i], 32);
    }
    float inv = 1.0f / (float)max(e - s, 1);
    bool act = (g == 0) && (lr < 5);
    float v[8];
    if (act) {
        const float* pb = out + (size_t)n * NCLS + lr * 8;
        float4 p0 = *reinterpret_cast<const float4*>(pb);
        float4 p1 = *reinterpret_cast<const float4*>(pb + 4);
        v[0] = p0.x + a[0] * inv; v[1] = p0.y + a[1] * inv;
        v[2] = p0.z + a[2] * inv; v[3] = p0.w + a[3] * inv;
        v[4] = p1.x + a[4] * inv; v[5] = p1.y + a[5] * inv;
        v[6] = p1.z + a[6] * inv; v[7] = p1.w + a[7] * inv;
    } else {
#pragma unroll
        for (int i = 0; i < 8; ++i) v[i] = -INFINITY;
    }
    float m = v[0];
#pragma unroll
    for (int i = 1; i < 8; ++i) m = fmaxf(m, v[i]);
    m = fmaxf(m, __shfl_xor(m, 1));
    m = fmaxf(m, __shfl_xor(m, 2));
    m = fmaxf(m, __shfl_xor(m, 4));
    float ex = 0.f;
    if (act) {
#pragma unroll
        for (int i = 0; i < 8; ++i) ex += expf(v[i] - m);
    }
    ex += __shfl_xor(ex, 1);
    ex += __shfl_xor(ex, 2);
    ex += __shfl_xor(ex, 4);
    float ls = logf(ex);
    if (act) {
        float* ob = out + (size_t)n * NCLS + lr * 8;
        float4 o0, o1;
        o0.x = v[0] - m - ls; o0.y = v[1] - m - ls; o0.z = v[2] - m - ls; o0.w = v[3] - m - ls;
        o1.x = v[4] - m - ls; o1.y = v[5] - m - ls; o1.z = v[6] - m - ls; o1.w = v[7] - m - ls;
        *reinterpret_cast<float4*>(ob) = o0;
        *reinterpret_cast<float4*>(ob + 4) = o1;
    }
}

// ---------------- launch ----------------

static inline size_t align256(size_t x) { return (x + 255) & ~(size_t)255; }

extern "C" void kernel_launch(void* const* d_in, const int* in_sizes, int n_in,
                              void* d_out, int out_size, void* d_ws, size_t ws_size,
                              hipStream_t stream) {
    const float* x    = (const float*)d_in[0];
    const int*   ei   = (const int*)d_in[1];
    const float* W1l  = (const float*)d_in[2];
    const float* b1   = (const float*)d_in[3];
    const float* W1r  = (const float*)d_in[4];
    const float* W2l  = (const float*)d_in[5];
    const float* b2   = (const float*)d_in[6];
    const float* W2r  = (const float*)d_in[7];
    float* out = (float*)d_out;

    const int N = N_NODES;
    const int E = in_sizes[1] / 2;
    const int* srcArr = ei;
    const int* dstArr = ei + E;

    char* ws = (char*)d_ws;
    size_t off = 0;
    auto alloc = [&](size_t bytes) { size_t o = off; off = align256(off + bytes); return o; };
    int*    cnt      = (int*)(ws + alloc((size_t)N * 4));
    int*    rowstart = (int*)(ws + alloc((size_t)(N + 1) * 4));
    int*    fillpos  = (int*)(ws + alloc((size_t)N * 4));
    int*    col      = (int*)(ws + alloc((size_t)E * 4));
    int*    bsum     = (int*)(ws + alloc(1024 * 4));
    ushort* xb       = (ushort*)(ws + alloc((size_t)NPAD * F_IN * 2));
    ushort* aggb     = (ushort*)(ws + alloc((size_t)NPAD * F_IN * 2));
    ushort* hWb      = (ushort*)(ws + alloc((size_t)NPAD * WPAD * 2));
    ushort* Wb1      = (ushort*)(ws + alloc((size_t)256 * 256 * 2));
    ushort* Wb2      = (ushort*)(ws + alloc((size_t)80 * 256 * 2));
    (void)ws_size; (void)n_in; (void)out_size;

    const int nbE = (E + 255) / 256;
    const int nbN = (N + 255) / 256;   // 196

    // 1. independent prep (cnt zero + x cast + weight packs)
    prep_kernel<<<6782, 256, 0, stream>>>(x, xb, W1l, W1r, W2l, W2r, Wb1, Wb2, cnt);
    // 2-6. CSR build (wide 3-kernel scan — single-block scan was 125us, reverted)
    count_kernel<<<nbE, 256, 0, stream>>>(dstArr, cnt, E);
    block_sum_kernel<<<nbN, 256, 0, stream>>>(cnt, bsum, N);
    scan_bsum_kernel<<<1, 1024, 0, stream>>>(bsum, nbN);
    scan_final_kernel<<<nbN, 256, 0, stream>>>(cnt, bsum, rowstart, fillpos, N, E);
    fill_kernel<<<nbE, 256, 0, stream>>>(srcArr, dstArr, fillpos, col, E);
    // 7. layer-1 mean aggregation
    agg128_kernel<<<(N + 3) / 4, 256, 0, stream>>>(xb, rowstart, col, aggb);
    // 8. fused gemm1+gemm2 (h stays in LDS)
    gemm12_kernel<<<NPAD / 128, 256, 0, stream>>>(aggb, xb, Wb1, b1, Wb2, b2, hWb, out);
    // 9. layer-2 aggregation + log_softmax
    agg40_lsm_kernel<<<(N + 3) / 4, 256, 0, stream>>>(hWb, rowstart, col, out);
}

// Round 7
// 166.685 us; speedup vs baseline: 1.7446x; 1.0483x over previous
//
#include <hip/hip_runtime.h>
#include <math.h>

#define N_NODES 50000
#define NPAD    50048      // 391 * 128
#define F_IN    128
#define HID     256
#define NCLS    40
#define WROW    80         // hWb row width (ushorts): cols 0-39 hW_l, 40-79 hW_r+b2

typedef __attribute__((ext_vector_type(8))) short bf16x8;
typedef __attribute__((ext_vector_type(4))) float f32x4;

__device__ inline ushort f2bf(float f) {
    uint u = __builtin_bit_cast(uint, f);
    u += 0x7FFF + ((u >> 16) & 1);          // round-to-nearest-even
    return (ushort)(u >> 16);
}
__device__ inline float bf2f(uint h16) {
    uint u = h16 << 16;
    return __builtin_bit_cast(float, u);
}

// ---------------- prep: zero cnt + cast x->bf16 + pack weights (one dispatch) ----------------
// blocks [0,196): cnt zero; [196,6446): cast_x (exactly 1.6M float4); [6446,6782): weight pack

__global__ void prep_kernel(const float* __restrict__ x, ushort* __restrict__ xb,
                            const float* __restrict__ W1l, const float* __restrict__ W1r,
                            const float* __restrict__ W2l, const float* __restrict__ W2r,
                            ushort* __restrict__ Wb1, ushort* __restrict__ Wb2,
                            int* __restrict__ cnt) {
    int b = blockIdx.x, t = threadIdx.x;
    if (b < 196) {
        int i = b * 256 + t;
        if (i < N_NODES) cnt[i] = 0;
    } else if (b < 6446) {
        int i = (b - 196) * 256 + t;     // < 1,600,000 exactly
        float4 v = *reinterpret_cast<const float4*>(x + (size_t)i * 4);
        ushort4 o;
        o.x = f2bf(v.x); o.y = f2bf(v.y); o.z = f2bf(v.z); o.w = f2bf(v.w);
        *reinterpret_cast<ushort4*>(xb + (size_t)i * 4) = o;
    } else {
        int i = (b - 6446) * 256 + t;    // < 86016 exactly
        if (i < 65536) {
            int n = i >> 8, k = i & 255;
            float v = (k < 128) ? W1l[n * 128 + k] : W1r[n * 128 + (k - 128)];
            Wb1[i] = f2bf(v);
        } else {
            int j = i - 65536;           // < 20480
            int n = j >> 8, k = j & 255;
            float v = (n < 40) ? W2l[n * 256 + k] : W2r[(n - 40) * 256 + k];
            Wb2[j] = f2bf(v);
        }
    }
}

// ---------------- CSR build ----------------

__global__ void count_kernel(const int* __restrict__ dst, int* __restrict__ cnt, int E) {
    int i = blockIdx.x * blockDim.x + threadIdx.x;
    if (i < E) atomicAdd(&cnt[dst[i]], 1);
}

__global__ void block_sum_kernel(const int* __restrict__ cnt, int* __restrict__ bsum, int N) {
    __shared__ int sdata[256];
    int i = blockIdx.x * 256 + threadIdx.x;
    sdata[threadIdx.x] = (i < N) ? cnt[i] : 0;
    __syncthreads();
    for (int off = 128; off; off >>= 1) {
        if (threadIdx.x < off) sdata[threadIdx.x] += sdata[threadIdx.x + off];
        __syncthreads();
    }
    if (threadIdx.x == 0) bsum[blockIdx.x] = sdata[0];
}

// scan of raw bsum folded in: every block scans the (<=256) block sums in LDS
__global__ void scan_final_kernel(const int* __restrict__ cnt, const int* __restrict__ bsum,
                                  int* __restrict__ rowstart, int* __restrict__ fillpos,
                                  int N, int E, int nb) {
    __shared__ int sb[256];
    __shared__ int sdata[256];
    int t = threadIdx.x;
    // scan block sums (inclusive) in LDS
    sb[t] = (t < nb) ? bsum[t] : 0;
    __syncthreads();
    for (int off = 1; off < 256; off <<= 1) {
        int u = (t >= off) ? sb[t - off] : 0;
        __syncthreads();
        sb[t] += u;
        __syncthreads();
    }
    int blkpre = (blockIdx.x == 0) ? 0 : sb[blockIdx.x - 1];
    // per-block scan of cnt
    int i = blockIdx.x * 256 + t;
    int v = (i < N) ? cnt[i] : 0;
    sdata[t] = v;
    __syncthreads();
    for (int off = 1; off < 256; off <<= 1) {
        int u = (t >= off) ? sdata[t - off] : 0;
        __syncthreads();
        sdata[t] += u;
        __syncthreads();
    }
    if (i < N) {
        int r = blkpre + sdata[t] - v;
        rowstart[i] = r;
        fillpos[i]  = r;
    }
    if (i == 0) rowstart[N] = E;
}

__global__ void fill_kernel(const int* __restrict__ src, const int* __restrict__ dst,
                            int* __restrict__ fillpos, int* __restrict__ col, int E) {
    int i = blockIdx.x * blockDim.x + threadIdx.x;
    if (i < E) {
        int p = atomicAdd(&fillpos[dst[i]], 1);
        col[p] = src[i];
    }
}

// ---------------- mean aggregation layer 1 ----------------
// 4 groups x 16 lanes x 16B; 2x unrolled -> 8 edges in flight per wave

__global__ __launch_bounds__(256) void agg128_kernel(const ushort* __restrict__ xb,
                                                     const int* __restrict__ rowstart,
                                                     const int* __restrict__ col,
                                                     ushort* __restrict__ aggb) {
    int wid = threadIdx.x >> 6, l = threadIdx.x & 63;
    int n = blockIdx.x * 4 + wid;
    if (n >= N_NODES) return;
    int g = l >> 4, lr = l & 15;
    int s = rowstart[n], e = rowstart[n + 1];
    float a[8] = {}, b[8] = {};
    int j = s + g;
    for (; j + 4 < e; j += 8) {
        int c0 = col[j], c1 = col[j + 4];
        uint4 v0 = *reinterpret_cast<const uint4*>(xb + (size_t)c0 * F_IN + lr * 8);
        uint4 v1 = *reinterpret_cast<const uint4*>(xb + (size_t)c1 * F_IN + lr * 8);
        a[0] += bf2f(v0.x & 0xffffu); a[1] += bf2f(v0.x >> 16);
        a[2] += bf2f(v0.y & 0xffffu); a[3] += bf2f(v0.y >> 16);
        a[4] += bf2f(v0.z & 0xffffu); a[5] += bf2f(v0.z >> 16);
        a[6] += bf2f(v0.w & 0xffffu); a[7] += bf2f(v0.w >> 16);
        b[0] += bf2f(v1.x & 0xffffu); b[1] += bf2f(v1.x >> 16);
        b[2] += bf2f(v1.y & 0xffffu); b[3] += bf2f(v1.y >> 16);
        b[4] += bf2f(v1.z & 0xffffu); b[5] += bf2f(v1.z >> 16);
        b[6] += bf2f(v1.w & 0xffffu); b[7] += bf2f(v1.w >> 16);
    }
    if (j < e) {
        int c = col[j];
        uint4 v = *reinterpret_cast<const uint4*>(xb + (size_t)c * F_IN + lr * 8);
        a[0] += bf2f(v.x & 0xffffu); a[1] += bf2f(v.x >> 16);
        a[2] += bf2f(v.y & 0xffffu); a[3] += bf2f(v.y >> 16);
        a[4] += bf2f(v.z & 0xffffu); a[5] += bf2f(v.z >> 16);
        a[6] += bf2f(v.w & 0xffffu); a[7] += bf2f(v.w >> 16);
    }
#pragma unroll
    for (int i = 0; i < 8; ++i) {
        a[i] += b[i];
        a[i] += __shfl_xor(a[i], 16);
        a[i] += __shfl_xor(a[i], 32);
    }
    if (g == 0) {
        float inv = 1.0f / (float)max(e - s, 1);
        uint4 o;
        o.x = (uint)f2bf(a[0] * inv) | ((uint)f2bf(a[1] * inv) << 16);
        o.y = (uint)f2bf(a[2] * inv) | ((uint)f2bf(a[3] * inv) << 16);
        o.z = (uint)f2bf(a[4] * inv) | ((uint)f2bf(a[5] * inv) << 16);
        o.w = (uint)f2bf(a[6] * inv) | ((uint)f2bf(a[7] * inv) << 16);
        *reinterpret_cast<uint4*>(aggb + (size_t)n * F_IN + lr * 8) = o;
    }
}

// ---------------- fused GEMM1+GEMM2 ----------------
// Phase 1: h = relu([agg|x] @ Wb1.T + b1), Wb1 staged per-128-col half in 64KB LDS.
// Phase 2: h tile -> same LDS (bf16, swizzled; h never touches global).
// Phase 3: hWb[row][0..39] = h @ W2l.T ; hWb[row][40..79] = h @ W2r.T + b2 (all bf16).

__global__ __launch_bounds__(256, 2) void gemm12_kernel(const ushort* __restrict__ aggb,
                                                        const ushort* __restrict__ xb,
                                                        const ushort* __restrict__ Wb1,
                                                        const float* __restrict__ b1,
                                                        const ushort* __restrict__ Wb2,
                                                        const float* __restrict__ b2,
                                                        ushort* __restrict__ hWb) {
    __shared__ __align__(16) char S[128 * 512];   // 64 KiB: B1-half staging, then h tile
    const int t = threadIdx.x, w = t >> 6, l = t & 63;
    const int bm = blockIdx.x * 128;
    const int lr = l & 15, lg = l >> 4;

    f32x4 acc[2][16] = {};
#pragma unroll
    for (int half = 0; half < 2; ++half) {
        // stage B1 rows [half*128, half*128+128), swizzled
        for (int i = t; i < 128 * 32; i += 256) {
            int n = i >> 5, k8 = (i & 31) * 8;
            uint4 v = *reinterpret_cast<const uint4*>(Wb1 + (size_t)(half * 128 + n) * 256 + k8);
            *reinterpret_cast<uint4*>(S + ((n * 512 + k8 * 2) ^ ((n & 7) << 4))) = v;
        }
        __syncthreads();
#pragma unroll
        for (int kt = 0; kt < 8; ++kt) {
            const ushort* Ap = (kt < 4) ? aggb : xb;
            int kb = kt * 32 - ((kt < 4) ? 0 : 128) + lg * 8;
            bf16x8 a0 = *reinterpret_cast<const bf16x8*>(Ap + (size_t)(bm + w * 32 + lr) * F_IN + kb);
            bf16x8 a1 = *reinterpret_cast<const bf16x8*>(Ap + (size_t)(bm + w * 32 + 16 + lr) * F_IN + kb);
            int kbyte = kt * 64 + lg * 16;
#pragma unroll
            for (int j = 0; j < 8; ++j) {
                int nl = j * 16 + lr;
                bf16x8 b = *reinterpret_cast<const bf16x8*>(S + ((nl * 512 + kbyte) ^ ((nl & 7) << 4)));
                acc[0][half * 8 + j] = __builtin_amdgcn_mfma_f32_16x16x32_bf16(a0, b, acc[0][half * 8 + j], 0, 0, 0);
                acc[1][half * 8 + j] = __builtin_amdgcn_mfma_f32_16x16x32_bf16(a1, b, acc[1][half * 8 + j], 0, 0, 0);
            }
        }
        __syncthreads();   // B reads done before restage / h write
    }

    // write h tile (128 x 256 bf16) into S, swizzled, row stride 512B
#pragma unroll
    for (int j = 0; j < 16; ++j) {
        int c = j * 16 + lr;
        float bias = b1[c];
#pragma unroll
        for (int m = 0; m < 2; ++m) {
            int rowb = w * 32 + m * 16 + lg * 4;
#pragma unroll
            for (int r = 0; r < 4; ++r) {
                float v = fmaxf(acc[m][j][r] + bias, 0.f);
                int row = rowb + r;
                *reinterpret_cast<ushort*>(S + ((row * 512 + c * 2) ^ ((row & 7) << 4))) = f2bf(v);
            }
        }
    }
    __syncthreads();

    // GEMM2: A from LDS h, B = Wb2 from global (L2)
    f32x4 acc2[2][5] = {};
#pragma unroll
    for (int kt = 0; kt < 8; ++kt) {
        int kbyte = kt * 64 + lg * 16;
        int r0 = w * 32 + lr, r1 = r0 + 16;
        bf16x8 a0 = *reinterpret_cast<const bf16x8*>(S + ((r0 * 512 + kbyte) ^ ((r0 & 7) << 4)));
        bf16x8 a1 = *reinterpret_cast<const bf16x8*>(S + ((r1 * 512 + kbyte) ^ ((r1 & 7) << 4)));
#pragma unroll
        for (int j = 0; j < 5; ++j) {
            int nl = j * 16 + lr;
            bf16x8 b = *reinterpret_cast<const bf16x8*>(Wb2 + (size_t)nl * 256 + kt * 32 + lg * 8);
            acc2[0][j] = __builtin_amdgcn_mfma_f32_16x16x32_bf16(a0, b, acc2[0][j], 0, 0, 0);
            acc2[1][j] = __builtin_amdgcn_mfma_f32_16x16x32_bf16(a1, b, acc2[1][j], 0, 0, 0);
        }
    }
#pragma unroll
    for (int m = 0; m < 2; ++m) {
        int rbase = bm + w * 32 + m * 16 + lg * 4;
#pragma unroll
        for (int j = 0; j < 5; ++j) {
            int cfull = j * 16 + lr;
            float bias = (cfull >= 40) ? b2[cfull - 40] : 0.f;
#pragma unroll
            for (int r = 0; r < 4; ++r) {
                int row = rbase + r;
                hWb[(size_t)row * WROW + cfull] = f2bf(acc2[m][j][r] + bias);
            }
        }
    }
}

// ---------------- fused: out = log_softmax(self + mean_j hW_j) ----------------
// 8 groups; lanes lr<5 load 16B each (80B row); 2x unrolled -> 16 edges in flight

__global__ __launch_bounds__(256) void agg40_lsm_kernel(const ushort* __restrict__ hWb,
                                                        const int* __restrict__ rowstart,
                                                        const int* __restrict__ col,
                                                        float* __restrict__ out) {
    int wid = threadIdx.x >> 6, l = threadIdx.x & 63;
    int n = blockIdx.x * 4 + wid;
    if (n >= N_NODES) return;
    int g = l >> 3, lr = l & 7;
    bool ld = lr < 5;
    int s = rowstart[n], e = rowstart[n + 1];
    float a[8] = {}, b[8] = {};
    int j = s + g;
    for (; j + 8 < e; j += 16) {
        int c0 = col[j], c1 = col[j + 8];
        if (ld) {
            uint4 v0 = *reinterpret_cast<const uint4*>(hWb + (size_t)c0 * WROW + lr * 8);
            uint4 v1 = *reinterpret_cast<const uint4*>(hWb + (size_t)c1 * WROW + lr * 8);
            a[0] += bf2f(v0.x & 0xffffu); a[1] += bf2f(v0.x >> 16);
            a[2] += bf2f(v0.y & 0xffffu); a[3] += bf2f(v0.y >> 16);
            a[4] += bf2f(v0.z & 0xffffu); a[5] += bf2f(v0.z >> 16);
            a[6] += bf2f(v0.w & 0xffffu); a[7] += bf2f(v0.w >> 16);
            b[0] += bf2f(v1.x & 0xffffu); b[1] += bf2f(v1.x >> 16);
            b[2] += bf2f(v1.y & 0xffffu); b[3] += bf2f(v1.y >> 16);
            b[4] += bf2f(v1.z & 0xffffu); b[5] += bf2f(v1.z >> 16);
            b[6] += bf2f(v1.w & 0xffffu); b[7] += bf2f(v1.w >> 16);
        }
    }
    if (j < e) {
        int c = col[j];
        if (ld) {
            uint4 v = *reinterpret_cast<const uint4*>(hWb + (size_t)c * WROW + lr * 8);
            a[0] += bf2f(v.x & 0xffffu); a[1] += bf2f(v.x >> 16);
            a[2] += bf2f(v.y & 0xffffu); a[3] += bf2f(v.y >> 16);
            a[4] += bf2f(v.z & 0xffffu); a[5] += bf2f(v.z >> 16);
            a[6] += bf2f(v.w & 0xffffu); a[7] += bf2f(v.w >> 16);
        }
    }
#pragma unroll
    for (int i = 0; i < 8; ++i) {
        a[i] += b[i];
        a[i] += __shfl_xor(a[i], 8);
        a[i] += __shfl_xor(a[i], 16);
        a[i] += __shfl_xor(a[i], 32);
    }
    float inv = 1.0f / (float)max(e - s, 1);
    bool act = (g == 0) && ld;
    float v[8];
    if (act) {
        // self part: cols 40-79 of own row (hW_r + b2), bf16
        uint4 sv = *reinterpret_cast<const uint4*>(hWb + (size_t)n * WROW + 40 + lr * 8);
        v[0] = bf2f(sv.x & 0xffffu) + a[0] * inv; v[1] = bf2f(sv.x >> 16) + a[1] * inv;
        v[2] = bf2f(sv.y & 0xffffu) + a[2] * inv; v[3] = bf2f(sv.y >> 16) + a[3] * inv;
        v[4] = bf2f(sv.z & 0xffffu) + a[4] * inv; v[5] = bf2f(sv.z >> 16) + a[5] * inv;
        v[6] = bf2f(sv.w & 0xffffu) + a[6] * inv; v[7] = bf2f(sv.w >> 16) + a[7] * inv;
    } else {
#pragma unroll
        for (int i = 0; i < 8; ++i) v[i] = -INFINITY;
    }
    float m = v[0];
#pragma unroll
    for (int i = 1; i < 8; ++i) m = fmaxf(m, v[i]);
    m = fmaxf(m, __shfl_xor(m, 1));
    m = fmaxf(m, __shfl_xor(m, 2));
    m = fmaxf(m, __shfl_xor(m, 4));
    float ex = 0.f;
    if (act) {
#pragma unroll
        for (int i = 0; i < 8; ++i) ex += expf(v[i] - m);
    }
    ex += __shfl_xor(ex, 1);
    ex += __shfl_xor(ex, 2);
    ex += __shfl_xor(ex, 4);
    float ls = logf(ex);
    if (act) {
        float* ob = out + (size_t)n * NCLS + lr * 8;
        float4 o0, o1;
        o0.x = v[0] - m - ls; o0.y = v[1] - m - ls; o0.z = v[2] - m - ls; o0.w = v[3] - m - ls;
        o1.x = v[4] - m - ls; o1.y = v[5] - m - ls; o1.z = v[6] - m - ls; o1.w = v[7] - m - ls;
        *reinterpret_cast<float4*>(ob) = o0;
        *reinterpret_cast<float4*>(ob + 4) = o1;
    }
}

// ---------------- launch ----------------

static inline size_t align256(size_t x) { return (x + 255) & ~(size_t)255; }

extern "C" void kernel_launch(void* const* d_in, const int* in_sizes, int n_in,
                              void* d_out, int out_size, void* d_ws, size_t ws_size,
                              hipStream_t stream) {
    const float* x    = (const float*)d_in[0];
    const int*   ei   = (const int*)d_in[1];
    const float* W1l  = (const float*)d_in[2];
    const float* b1   = (const float*)d_in[3];
    const float* W1r  = (const float*)d_in[4];
    const float* W2l  = (const float*)d_in[5];
    const float* b2   = (const float*)d_in[6];
    const float* W2r  = (const float*)d_in[7];
    float* out = (float*)d_out;

    const int N = N_NODES;
    const int E = in_sizes[1] / 2;
    const int* srcArr = ei;
    const int* dstArr = ei + E;

    char* ws = (char*)d_ws;
    size_t off = 0;
    auto alloc = [&](size_t bytes) { size_t o = off; off = align256(off + bytes); return o; };
    int*    cnt      = (int*)(ws + alloc((size_t)N * 4));
    int*    rowstart = (int*)(ws + alloc((size_t)(N + 1) * 4));
    int*    fillpos  = (int*)(ws + alloc((size_t)N * 4));
    int*    col      = (int*)(ws + alloc((size_t)E * 4));
    int*    bsum     = (int*)(ws + alloc(1024 * 4));
    ushort* xb       = (ushort*)(ws + alloc((size_t)NPAD * F_IN * 2));
    ushort* aggb     = (ushort*)(ws + alloc((size_t)NPAD * F_IN * 2));
    ushort* hWb      = (ushort*)(ws + alloc((size_t)NPAD * WROW * 2));
    ushort* Wb1      = (ushort*)(ws + alloc((size_t)256 * 256 * 2));
    ushort* Wb2      = (ushort*)(ws + alloc((size_t)80 * 256 * 2));
    (void)ws_size; (void)n_in; (void)out_size;

    const int nbE = (E + 255) / 256;
    const int nbN = (N + 255) / 256;   // 196

    // 1. independent prep (cnt zero + x cast + weight packs)
    prep_kernel<<<6782, 256, 0, stream>>>(x, xb, W1l, W1r, W2l, W2r, Wb1, Wb2, cnt);
    // 2-5. CSR build (bsum scan folded into scan_final)
    count_kernel<<<nbE, 256, 0, stream>>>(dstArr, cnt, E);
    block_sum_kernel<<<nbN, 256, 0, stream>>>(cnt, bsum, N);
    scan_final_kernel<<<nbN, 256, 0, stream>>>(cnt, bsum, rowstart, fillpos, N, E, nbN);
    fill_kernel<<<nbE, 256, 0, stream>>>(srcArr, dstArr, fillpos, col, E);
    // 6. layer-1 mean aggregation (2x unrolled gather)
    agg128_kernel<<<(N + 3) / 4, 256, 0, stream>>>(xb, rowstart, col, aggb);
    // 7. fused gemm1+gemm2 (h stays in LDS; both halves of layer-2 output in hWb)
    gemm12_kernel<<<NPAD / 128, 256, 0, stream>>>(aggb, xb, Wb1, b1, Wb2, b2, hWb);
    // 8. layer-2 aggregation + self + log_softmax
    agg40_lsm_kernel<<<(N + 3) / 4, 256, 0, stream>>>(hWb, rowstart, col, out);
}